// Round 15
// baseline (239.863 us; speedup 1.0000x reference)
//
#include <hip/hip_runtime.h>
#include <hip/hip_bf16.h>

#define DI __device__ __forceinline__

namespace {
constexpr int N_ = 128, S_ = 32, P_ = 16, F_ = 256, H_ = 4, NH_ = 128;
constexpr int SP_ = S_ * P_;          // 512
constexpr int ROWS_ = N_ * SP_;       // 65536
constexpr int GC_ = H_ * NH_;         // 512
constexpr float SLOPE_ = 0.2f;
constexpr int OUT_ELEMS = N_ * SP_ * NH_;    // 8,388,608
}

DI float lrelu(float x) { return fmaxf(x, SLOPE_ * x); }   // exact for slope<1

DI unsigned short f2h(float x) {
    _Float16 h = (_Float16)x;
    return __builtin_bit_cast(unsigned short, h);
}
DI float h2f(unsigned short b) {
    return (float)__builtin_bit_cast(_Float16, b);
}

typedef __fp16   fp16x2 __attribute__((ext_vector_type(2)));
typedef _Float16 f16x8 __attribute__((ext_vector_type(8)));
typedef float    f32x4 __attribute__((ext_vector_type(4)));

DI unsigned int pk2(float a, float b) {          // packed f16 convert (RTZ)
    fp16x2 r = __builtin_amdgcn_cvt_pkrtz(a, b);
    return __builtin_bit_cast(unsigned int, r);
}

DI f32x4 mfma16h(uint4 a, uint4 b, f32x4 c) {
    return __builtin_amdgcn_mfma_f32_16x16x32_f16(
        __builtin_bit_cast(f16x8, a), __builtin_bit_cast(f16x8, b), c, 0, 0, 0);
}

// ---------------------------------------------------------------------------
__global__ __launch_bounds__(256) void prep_kernel(
    const float* __restrict__ Wl, const float* __restrict__ Wr,
    const float* __restrict__ aw, float* __restrict__ wls, float* __restrict__ wrs) {
    int t = blockIdx.x * 256 + threadIdx.x;   // 0..2047
    int which = t >> 10;
    int f = (t & 1023) >> 2;
    int h = t & 3;
    const float* W = which ? Wr : Wl;
    const float* a = aw + which * NH_;
    const float* wrow = W + (size_t)f * GC_ + h * NH_;
    float s = 0.f;
    for (int k = 0; k < NH_; ++k) s += wrow[k] * a[k];
    (which ? wrs : wls)[f * H_ + h] = s;
}

// ---------------------------------------------------------------------------
__global__ __launch_bounds__(256) void prep_bt(
    const float* __restrict__ Wr, unsigned short* __restrict__ bth,
    unsigned short* __restrict__ btl) {
    int t = blockIdx.x * 256 + threadIdx.x;   // 0..16383
    int col = t >> 5, k0 = (t & 31) * 8;
    union { unsigned short us[8]; uint4 v; } ph, pl;
#pragma unroll
    for (int e = 0; e < 8; ++e) {
        float v = Wr[(size_t)(k0 + e) * GC_ + col] * 256.0f;
        unsigned short hi = f2h(v);
        ph.us[e] = hi;
        pl.us[e] = f2h(v - h2f(hi));
    }
    *(uint4*)&bth[col * F_ + k0] = ph.v;
    *(uint4*)&btl[col * F_ + k0] = pl.v;
}

// ---------------------------------------------------------------------------
__global__ __launch_bounds__(256) void score_kernel(
    const float* __restrict__ hm, const float* __restrict__ wls,
    const float* __restrict__ wrs, float* __restrict__ sl, float* __restrict__ sr) {
    int r = blockIdx.x * 256 + threadIdx.x;    // 0..65535
    const float4* hr  = (const float4*)(hm + (size_t)r * F_);
    const float4* wl4 = (const float4*)wls;
    const float4* wr4 = (const float4*)wrs;
    float4 al = {0.f,0.f,0.f,0.f}, ar = {0.f,0.f,0.f,0.f};
    for (int f0 = 0; f0 < F_; f0 += 4) {
        float4 hv = hr[f0 >> 2];
        float hx[4] = {hv.x, hv.y, hv.z, hv.w};
#pragma unroll
        for (int u = 0; u < 4; ++u) {
            float4 wl = wl4[f0 + u], wr = wr4[f0 + u];
            al.x += hx[u] * wl.x; al.y += hx[u] * wl.y;
            al.z += hx[u] * wl.z; al.w += hx[u] * wl.w;
            ar.x += hx[u] * wr.x; ar.y += hx[u] * wr.y;
            ar.z += hx[u] * wr.z; ar.w += hx[u] * wr.w;
        }
    }
    int n = r >> 9, sp = r & 511;
    ((float4*)sl)[sp * N_ + n] = al;
    ((float4*)sr)[sp * N_ + n] = ar;
}

// ---------------------------------------------------------------------------
// Fused per-sp kernel; P computed ONCE per (i,j,h) in the PV phase:
//   scores -> parallel max1/max2 -> pure-GEMM K-loop (A dbuf, B frags, MFMA)
//   -> all-heads gt epilogue (1 barrier) -> barrier-free PV per head:
//   {32 exps, shfl-reduce sum, scale, a_out scalar stores ([i][j][h] layout,
//   L2 write-combines the 4 h-planes), f2h pack, MFMA} -> out epilogue.
__global__ __launch_bounds__(512, 2) void gat_fused(
    const float* __restrict__ sl_g, const float* __restrict__ sr_g,
    const float* __restrict__ hm,
    const unsigned short* __restrict__ bth, const unsigned short* __restrict__ btl,
    float* __restrict__ a_out, float* __restrict__ out) {
    constexpr int PA = 40;
    __shared__ __align__(16) unsigned char SMEM[136832];
    unsigned short* Ah0 = (unsigned short*)SMEM;               // [128*PA]
    unsigned short* Ah1 = Ah0 + 128 * PA;
    unsigned short* Al0 = Ah1 + 128 * PA;
    unsigned short* Al1 = Al0 + 128 * PA;                      // 40960 B total
    unsigned short* gt4 = (unsigned short*)SMEM;               // [4][128][128] after GEMM
    float4* sr4 = (float4*)(SMEM + 131072);                    // 2048 B
    float*  slh = (float*)(SMEM + 133120);                     // [4][132] = 2112 B
    float*  mx1 = (float*)(SMEM + 135232);
    float*  mx2 = (float*)(SMEM + 135248);
    int*    id1 = (int*)(SMEM + 135264);
    float*  pm1 = (float*)(SMEM + 135280);                     // [4][32]
    float*  pm2 = pm1 + 128;                                   // [4][32]
    int*    pid = (int*)(pm2 + 128);                           // [4][32]

    int sp = blockIdx.x;
    int t = threadIdx.x;
    int w = t >> 6, l = t & 63;
    int ls = l & 15, kg = l >> 4;

    // ---- load scores ----
    if (t < 128) {
        float4 v = ((const float4*)sl_g)[sp * N_ + t];
        slh[0 * 132 + t] = v.x; slh[1 * 132 + t] = v.y;
        slh[2 * 132 + t] = v.z; slh[3 * 132 + t] = v.w;
    } else if (t < 256) {
        sr4[t - 128] = ((const float4*)sr_g)[sp * N_ + (t - 128)];
    }
    __syncthreads();

    // ---- issue step-0 A loads early (drain under max-scan) ----
    int arow = t >> 2, akc = (t & 3) * 8;
    const float* abase = hm + ((size_t)arow * 512 + sp) * 256 + akc;
    float4 s0 = *(const float4*)(abase);
    float4 s1 = *(const float4*)(abase + 4);

    // ---- parallel max1/max2(+argmax) of sl per head ----
    if (t < 128) {
        int h = t >> 5, seg = t & 31;
        float m1 = -1e30f, m2 = -1e30f; int i1 = -1;
#pragma unroll
        for (int jj = 0; jj < 4; ++jj) {
            int j = seg * 4 + jj;
            float v = slh[h * 132 + j];
            if (v > m1) { m2 = m1; m1 = v; i1 = j; }
            else m2 = fmaxf(m2, v);
        }
        pm1[h * 32 + seg] = m1; pm2[h * 32 + seg] = m2; pid[h * 32 + seg] = i1;
    }
    __syncthreads();
    if (t < H_) {
        float m1 = -1e30f, m2 = -1e30f; int i1 = -1;
        for (int s = 0; s < 32; ++s) {
            float a1 = pm1[t * 32 + s], a2 = pm2[t * 32 + s]; int ai = pid[t * 32 + s];
            if (a1 > m1) { m2 = fmaxf(m1, a2); m1 = a1; i1 = ai; }
            else m2 = fmaxf(m2, a1);
        }
        mx1[t] = m1; mx2[t] = m2; id1[t] = i1;
    }

    // ---- convert + write A step-0 (pkrtz pairs) ----
    {
        float av[8] = {s0.x, s0.y, s0.z, s0.w, s1.x, s1.y, s1.z, s1.w};
        uint4 vh, vl;
        unsigned int* ph = (unsigned int*)&vh;
        unsigned int* pl = (unsigned int*)&vl;
#pragma unroll
        for (int e = 0; e < 8; e += 2) {
            unsigned int hp = pk2(av[e], av[e + 1]);
            float r0 = av[e]     - h2f((unsigned short)(hp & 0xffff));
            float r1 = av[e + 1] - h2f((unsigned short)(hp >> 16));
            ph[e >> 1] = hp;
            pl[e >> 1] = pk2(r0, r1);
        }
        *(uint4*)&Ah0[arow * PA + akc] = vh;
        *(uint4*)&Al0[arow * PA + akc] = vl;
    }
    __syncthreads();

    f32x4 acc[8][4];
#pragma unroll
    for (int m = 0; m < 8; ++m)
#pragma unroll
        for (int n = 0; n < 4; ++n) acc[m][n] = (f32x4){0.f, 0.f, 0.f, 0.f};

    // ---- pure-GEMM K-loop ----
    for (int step = 0; step < 8; ++step) {
        unsigned short* AhC = (step & 1) ? Ah1 : Ah0;
        unsigned short* AlC = (step & 1) ? Al1 : Al0;
        unsigned short* AhN = (step & 1) ? Ah0 : Ah1;
        unsigned short* AlN = (step & 1) ? Al0 : Al1;
        float4 n0, n1;
        if (step < 7) {
            n0 = *(const float4*)(abase + (step + 1) * 32);
            n1 = *(const float4*)(abase + (step + 1) * 32 + 4);
        }
        int kglob = step * 32 + kg * 8;
        uint4 fbh[4], fbl[4];
#pragma unroll
        for (int n = 0; n < 4; ++n) {
            int c = n * 128 + w * 16 + ls;
            fbh[n] = *(const uint4*)&bth[(size_t)c * F_ + kglob];
            fbl[n] = *(const uint4*)&btl[(size_t)c * F_ + kglob];
        }
#pragma unroll
        for (int m = 0; m < 8; ++m) {
            int row = m * 16 + ls;
            uint4 fah = *(const uint4*)&AhC[row * PA + kg * 8];
            uint4 fal = *(const uint4*)&AlC[row * PA + kg * 8];
#pragma unroll
            for (int n = 0; n < 4; ++n) {
                acc[m][n] = mfma16h(fah, fbh[n], acc[m][n]);
                acc[m][n] = mfma16h(fah, fbl[n], acc[m][n]);
                acc[m][n] = mfma16h(fal, fbh[n], acc[m][n]);
            }
        }
        if (step < 7) {
            float av[8] = {n0.x, n0.y, n0.z, n0.w, n1.x, n1.y, n1.z, n1.w};
            uint4 vh, vl;
            unsigned int* ph = (unsigned int*)&vh;
            unsigned int* pl = (unsigned int*)&vl;
#pragma unroll
            for (int e = 0; e < 8; e += 2) {
                unsigned int hp = pk2(av[e], av[e + 1]);
                float r0 = av[e]     - h2f((unsigned short)(hp & 0xffff));
                float r1 = av[e + 1] - h2f((unsigned short)(hp >> 16));
                ph[e >> 1] = hp;
                pl[e >> 1] = pk2(r0, r1);
            }
            *(uint4*)&AhN[arow * PA + akc] = vh;
            *(uint4*)&AlN[arow * PA + akc] = vl;
        }
        __syncthreads();
    }

    // ---- GEMM epilogue: all-heads gt (A buffers dead; union reuse) ----
    int fl  = w * 16 + ls;
    int swz = (ls & 7) << 3;
    constexpr float gs = 0.00390625f;
#pragma unroll
    for (int m = 0; m < 8; ++m) {
        int nx = (m * 16 + kg * 4) ^ swz;
#pragma unroll
        for (int h = 0; h < H_; ++h) {
            uint2 pk;
            pk.x = pk2(acc[m][h][0] * gs, acc[m][h][1] * gs);
            pk.y = pk2(acc[m][h][2] * gs, acc[m][h][3] * gs);
            *(uint2*)&gt4[h * 16384 + fl * 128 + nx] = pk;
        }
    }
    __syncthreads();

    // ---- PV phase (barrier-free): P computed once per (i,j,h) ----
    f32x4 aco[8];
#pragma unroll
    for (int n = 0; n < 8; ++n) aco[n] = (f32x4){0.f, 0.f, 0.f, 0.f};

    int i_my = w * 16 + ls;
    float* a_irow = a_out + (size_t)sp * 65536 + (size_t)i_my * 512;  // [i][j][h]

    for (int h = 0; h < H_; ++h) {
        float sri = ((const float*)&sr4[i_my])[h];
        float mh  = lrelu(sri + ((id1[h] == i_my) ? mx2[h] : mx1[h]));
        // 32 exps (unnormalized P), diag zero, partial sum
        float p[4][8];
        float psum = 0.f;
#pragma unroll
        for (int k0i = 0; k0i < 4; ++k0i) {
            int jb = k0i * 32 + kg * 8;
            float4 sa = *(const float4*)&slh[h * 132 + jb];
            float4 sb = *(const float4*)&slh[h * 132 + jb + 4];
            float sj[8] = {sa.x, sa.y, sa.z, sa.w, sb.x, sb.y, sb.z, sb.w};
#pragma unroll
            for (int e = 0; e < 8; ++e) {
                int j = jb + e;
                float v = (j == i_my) ? 0.f : __expf(lrelu(sri + sj[e]) - mh);
                p[k0i][e] = v;
                psum += v;
            }
        }
        // full row sum across the 4 kg-lanes sharing this row
        psum += __shfl_xor(psum, 16);
        psum += __shfl_xor(psum, 32);
        float sh = 1.f / psum;
        // scale, store a_out ([i][j][h] layout, h innermost), pack pa
        uint4 pa[4];
        float* a_h = a_irow + h;
#pragma unroll
        for (int k0i = 0; k0i < 4; ++k0i) {
            union { unsigned short us[8]; uint4 v; } pk;
            int jb = k0i * 32 + kg * 8;
#pragma unroll
            for (int e = 0; e < 8; ++e) {
                float v = p[k0i][e] * sh;
                a_h[(jb + e) * 4] = v;
                pk.us[e] = f2h(v);
            }
            pa[k0i] = pk.v;
        }
        // PV MFMA
        __builtin_amdgcn_s_setprio(1);
#pragma unroll
        for (int k0i = 0; k0i < 4; ++k0i) {
            int koff = k0i * 32 + kg * 8;
#pragma unroll
            for (int n = 0; n < 8; ++n) {
                int f = n * 16 + ls;
                uint4 fb = *(const uint4*)&gt4[h * 16384 + f * 128 + (koff ^ swz)];
                aco[n] = mfma16h(pa[k0i], fb, aco[n]);
            }
        }
        __builtin_amdgcn_s_setprio(0);
    }

    // ---- out epilogue ----
#pragma unroll
    for (int n = 0; n < 8; ++n) {
        int f = n * 16 + ls;
#pragma unroll
        for (int q = 0; q < 4; ++q)
            out[(size_t)(w * 16 + kg * 4 + q) * 65536 + (size_t)sp * NH_ + f] =
                aco[n][q] * 0.25f;
    }
}

// ---------------------------------------------------------------------------
extern "C" void kernel_launch(void* const* d_in, const int* in_sizes, int n_in,
                              void* d_out, int out_size, void* d_ws, size_t ws_size,
                              hipStream_t stream) {
    const float* hm = (const float*)d_in[0];
    const float* Wl = (const float*)d_in[1];
    const float* Wr = (const float*)d_in[2];
    const float* aw = (const float*)d_in[3];

    float* out   = (float*)d_out;
    float* a_out = out + OUT_ELEMS;

    char* ws = (char*)d_ws;
    float* sl  = (float*)ws;                                  // 1 MiB
    float* sr  = sl + SP_ * N_ * H_;                          // 1 MiB
    float* wls = sr + SP_ * N_ * H_;                          // 4 KiB
    float* wrs = wls + F_ * H_;                               // 4 KiB
    unsigned short* bth = (unsigned short*)(wrs + F_ * H_);   // 256 KiB
    unsigned short* btl = bth + GC_ * F_;                     // 256 KiB

    prep_kernel <<<8,           256, 0, stream>>>(Wl, Wr, aw, wls, wrs);
    prep_bt     <<<64,          256, 0, stream>>>(Wr, bth, btl);
    score_kernel<<<ROWS_ / 256, 256, 0, stream>>>(hm, wls, wrs, sl, sr);
    gat_fused   <<<SP_,         512, 0, stream>>>(sl, sr, hm, bth, btl, a_out, out);
}

// Round 16
// 147.019 us; speedup vs baseline: 1.6315x; 1.6315x over previous
//
#include <hip/hip_runtime.h>
#include <hip/hip_bf16.h>

#define DI __device__ __forceinline__

namespace {
constexpr int N_ = 128, S_ = 32, P_ = 16, F_ = 256, H_ = 4, NH_ = 128;
constexpr int SP_ = S_ * P_;          // 512
constexpr int ROWS_ = N_ * SP_;       // 65536
constexpr int GC_ = H_ * NH_;         // 512
constexpr float SLOPE_ = 0.2f;
constexpr int OUT_ELEMS = N_ * SP_ * NH_;    // 8,388,608
}

DI float lrelu(float x) { return fmaxf(x, SLOPE_ * x); }   // exact for slope<1

DI unsigned short f2h(float x) {
    _Float16 h = (_Float16)x;
    return __builtin_bit_cast(unsigned short, h);
}
DI float h2f(unsigned short b) {
    return (float)__builtin_bit_cast(_Float16, b);
}

typedef __fp16   fp16x2 __attribute__((ext_vector_type(2)));
typedef _Float16 f16x8 __attribute__((ext_vector_type(8)));
typedef float    f32x4 __attribute__((ext_vector_type(4)));

DI unsigned int pk2(float a, float b) {          // packed f16 convert (RTZ)
    fp16x2 r = __builtin_amdgcn_cvt_pkrtz(a, b);
    return __builtin_bit_cast(unsigned int, r);
}

DI f32x4 mfma16h(uint4 a, uint4 b, f32x4 c) {
    return __builtin_amdgcn_mfma_f32_16x16x32_f16(
        __builtin_bit_cast(f16x8, a), __builtin_bit_cast(f16x8, b), c, 0, 0, 0);
}

// ---------------------------------------------------------------------------
__global__ __launch_bounds__(256) void prep_kernel(
    const float* __restrict__ Wl, const float* __restrict__ Wr,
    const float* __restrict__ aw, float* __restrict__ wls, float* __restrict__ wrs) {
    int t = blockIdx.x * 256 + threadIdx.x;   // 0..2047
    int which = t >> 10;
    int f = (t & 1023) >> 2;
    int h = t & 3;
    const float* W = which ? Wr : Wl;
    const float* a = aw + which * NH_;
    const float* wrow = W + (size_t)f * GC_ + h * NH_;
    float s = 0.f;
    for (int k = 0; k < NH_; ++k) s += wrow[k] * a[k];
    (which ? wrs : wls)[f * H_ + h] = s;
}

// ---------------------------------------------------------------------------
__global__ __launch_bounds__(256) void prep_bt(
    const float* __restrict__ Wr, unsigned short* __restrict__ bth,
    unsigned short* __restrict__ btl) {
    int t = blockIdx.x * 256 + threadIdx.x;   // 0..16383
    int col = t >> 5, k0 = (t & 31) * 8;
    union { unsigned short us[8]; uint4 v; } ph, pl;
#pragma unroll
    for (int e = 0; e < 8; ++e) {
        float v = Wr[(size_t)(k0 + e) * GC_ + col] * 256.0f;
        unsigned short hi = f2h(v);
        ph.us[e] = hi;
        pl.us[e] = f2h(v - h2f(hi));
    }
    *(uint4*)&bth[col * F_ + k0] = ph.v;
    *(uint4*)&btl[col * F_ + k0] = pl.v;
}

// ---------------------------------------------------------------------------
__global__ __launch_bounds__(256) void score_kernel(
    const float* __restrict__ hm, const float* __restrict__ wls,
    const float* __restrict__ wrs, float* __restrict__ sl, float* __restrict__ sr) {
    int r = blockIdx.x * 256 + threadIdx.x;    // 0..65535
    const float4* hr  = (const float4*)(hm + (size_t)r * F_);
    const float4* wl4 = (const float4*)wls;
    const float4* wr4 = (const float4*)wrs;
    float4 al = {0.f,0.f,0.f,0.f}, ar = {0.f,0.f,0.f,0.f};
    for (int f0 = 0; f0 < F_; f0 += 4) {
        float4 hv = hr[f0 >> 2];
        float hx[4] = {hv.x, hv.y, hv.z, hv.w};
#pragma unroll
        for (int u = 0; u < 4; ++u) {
            float4 wl = wl4[f0 + u], wr = wr4[f0 + u];
            al.x += hx[u] * wl.x; al.y += hx[u] * wl.y;
            al.z += hx[u] * wl.z; al.w += hx[u] * wl.w;
            ar.x += hx[u] * wr.x; ar.y += hx[u] * wr.y;
            ar.z += hx[u] * wr.z; ar.w += hx[u] * wr.w;
        }
    }
    int n = r >> 9, sp = r & 511;
    ((float4*)sl)[sp * N_ + n] = al;
    ((float4*)sr)[sp * N_ + n] = ar;
}

// ---------------------------------------------------------------------------
// Fused per-sp kernel; P computed ONCE per (i,j,h), held packed-f16 in
// registers for all 4 heads, a_out written once as float4-over-h:
//   scores -> parallel max1/max2 -> pure-GEMM K-loop -> all-heads gt
//   epilogue (1 barrier) -> barrier-free PV (unrolled h): {32 exps,
//   shfl-reduce, pack pa_all[h], MFMA} -> a_out float4 stores -> out.
__global__ __launch_bounds__(512, 2) void gat_fused(
    const float* __restrict__ sl_g, const float* __restrict__ sr_g,
    const float* __restrict__ hm,
    const unsigned short* __restrict__ bth, const unsigned short* __restrict__ btl,
    float* __restrict__ a_out, float* __restrict__ out) {
    constexpr int PA = 40;
    __shared__ __align__(16) unsigned char SMEM[136832];
    unsigned short* Ah0 = (unsigned short*)SMEM;               // [128*PA]
    unsigned short* Ah1 = Ah0 + 128 * PA;
    unsigned short* Al0 = Ah1 + 128 * PA;
    unsigned short* Al1 = Al0 + 128 * PA;                      // 40960 B total
    unsigned short* gt4 = (unsigned short*)SMEM;               // [4][128][128] after GEMM
    float4* sr4 = (float4*)(SMEM + 131072);                    // 2048 B
    float*  slh = (float*)(SMEM + 133120);                     // [4][132] = 2112 B
    float*  mx1 = (float*)(SMEM + 135232);
    float*  mx2 = (float*)(SMEM + 135248);
    int*    id1 = (int*)(SMEM + 135264);
    float*  pm1 = (float*)(SMEM + 135280);                     // [4][32]
    float*  pm2 = pm1 + 128;                                   // [4][32]
    int*    pid = (int*)(pm2 + 128);                           // [4][32]

    int sp = blockIdx.x;
    int t = threadIdx.x;
    int w = t >> 6, l = t & 63;
    int ls = l & 15, kg = l >> 4;

    // ---- load scores ----
    if (t < 128) {
        float4 v = ((const float4*)sl_g)[sp * N_ + t];
        slh[0 * 132 + t] = v.x; slh[1 * 132 + t] = v.y;
        slh[2 * 132 + t] = v.z; slh[3 * 132 + t] = v.w;
    } else if (t < 256) {
        sr4[t - 128] = ((const float4*)sr_g)[sp * N_ + (t - 128)];
    }
    __syncthreads();

    // ---- issue step-0 A loads early (drain under max-scan) ----
    int arow = t >> 2, akc = (t & 3) * 8;
    const float* abase = hm + ((size_t)arow * 512 + sp) * 256 + akc;
    float4 s0 = *(const float4*)(abase);
    float4 s1 = *(const float4*)(abase + 4);

    // ---- parallel max1/max2(+argmax) of sl per head ----
    if (t < 128) {
        int h = t >> 5, seg = t & 31;
        float m1 = -1e30f, m2 = -1e30f; int i1 = -1;
#pragma unroll
        for (int jj = 0; jj < 4; ++jj) {
            int j = seg * 4 + jj;
            float v = slh[h * 132 + j];
            if (v > m1) { m2 = m1; m1 = v; i1 = j; }
            else m2 = fmaxf(m2, v);
        }
        pm1[h * 32 + seg] = m1; pm2[h * 32 + seg] = m2; pid[h * 32 + seg] = i1;
    }
    __syncthreads();
    if (t < H_) {
        float m1 = -1e30f, m2 = -1e30f; int i1 = -1;
        for (int s = 0; s < 32; ++s) {
            float a1 = pm1[t * 32 + s], a2 = pm2[t * 32 + s]; int ai = pid[t * 32 + s];
            if (a1 > m1) { m2 = fmaxf(m1, a2); m1 = a1; i1 = ai; }
            else m2 = fmaxf(m2, a1);
        }
        mx1[t] = m1; mx2[t] = m2; id1[t] = i1;
    }

    // ---- convert + write A step-0 (pkrtz pairs) ----
    {
        float av[8] = {s0.x, s0.y, s0.z, s0.w, s1.x, s1.y, s1.z, s1.w};
        uint4 vh, vl;
        unsigned int* ph = (unsigned int*)&vh;
        unsigned int* pl = (unsigned int*)&vl;
#pragma unroll
        for (int e = 0; e < 8; e += 2) {
            unsigned int hp = pk2(av[e], av[e + 1]);
            float r0 = av[e]     - h2f((unsigned short)(hp & 0xffff));
            float r1 = av[e + 1] - h2f((unsigned short)(hp >> 16));
            ph[e >> 1] = hp;
            pl[e >> 1] = pk2(r0, r1);
        }
        *(uint4*)&Ah0[arow * PA + akc] = vh;
        *(uint4*)&Al0[arow * PA + akc] = vl;
    }
    __syncthreads();

    f32x4 acc[8][4];
#pragma unroll
    for (int m = 0; m < 8; ++m)
#pragma unroll
        for (int n = 0; n < 4; ++n) acc[m][n] = (f32x4){0.f, 0.f, 0.f, 0.f};

    // ---- pure-GEMM K-loop ----
    for (int step = 0; step < 8; ++step) {
        unsigned short* AhC = (step & 1) ? Ah1 : Ah0;
        unsigned short* AlC = (step & 1) ? Al1 : Al0;
        unsigned short* AhN = (step & 1) ? Ah0 : Ah1;
        unsigned short* AlN = (step & 1) ? Al0 : Al1;
        float4 n0, n1;
        if (step < 7) {
            n0 = *(const float4*)(abase + (step + 1) * 32);
            n1 = *(const float4*)(abase + (step + 1) * 32 + 4);
        }
        int kglob = step * 32 + kg * 8;
        uint4 fbh[4], fbl[4];
#pragma unroll
        for (int n = 0; n < 4; ++n) {
            int c = n * 128 + w * 16 + ls;
            fbh[n] = *(const uint4*)&bth[(size_t)c * F_ + kglob];
            fbl[n] = *(const uint4*)&btl[(size_t)c * F_ + kglob];
        }
#pragma unroll
        for (int m = 0; m < 8; ++m) {
            int row = m * 16 + ls;
            uint4 fah = *(const uint4*)&AhC[row * PA + kg * 8];
            uint4 fal = *(const uint4*)&AlC[row * PA + kg * 8];
#pragma unroll
            for (int n = 0; n < 4; ++n) {
                acc[m][n] = mfma16h(fah, fbh[n], acc[m][n]);
                acc[m][n] = mfma16h(fah, fbl[n], acc[m][n]);
                acc[m][n] = mfma16h(fal, fbh[n], acc[m][n]);
            }
        }
        if (step < 7) {
            float av[8] = {n0.x, n0.y, n0.z, n0.w, n1.x, n1.y, n1.z, n1.w};
            uint4 vh, vl;
            unsigned int* ph = (unsigned int*)&vh;
            unsigned int* pl = (unsigned int*)&vl;
#pragma unroll
            for (int e = 0; e < 8; e += 2) {
                unsigned int hp = pk2(av[e], av[e + 1]);
                float r0 = av[e]     - h2f((unsigned short)(hp & 0xffff));
                float r1 = av[e + 1] - h2f((unsigned short)(hp >> 16));
                ph[e >> 1] = hp;
                pl[e >> 1] = pk2(r0, r1);
            }
            *(uint4*)&AhN[arow * PA + akc] = vh;
            *(uint4*)&AlN[arow * PA + akc] = vl;
        }
        __syncthreads();
    }

    // ---- GEMM epilogue: all-heads gt (A buffers dead; union reuse) ----
    int fl  = w * 16 + ls;
    int swz = (ls & 7) << 3;
    constexpr float gs = 0.00390625f;
#pragma unroll
    for (int m = 0; m < 8; ++m) {
        int nx = (m * 16 + kg * 4) ^ swz;
#pragma unroll
        for (int h = 0; h < H_; ++h) {
            uint2 pk;
            pk.x = pk2(acc[m][h][0] * gs, acc[m][h][1] * gs);
            pk.y = pk2(acc[m][h][2] * gs, acc[m][h][3] * gs);
            *(uint2*)&gt4[h * 16384 + fl * 128 + nx] = pk;
        }
    }
    __syncthreads();

    // ---- PV phase (barrier-free): P computed once, kept packed-f16 ----
    f32x4 aco[8];
#pragma unroll
    for (int n = 0; n < 8; ++n) aco[n] = (f32x4){0.f, 0.f, 0.f, 0.f};

    int i_my = w * 16 + ls;
    uint4 pa_all[4][4];          // [head][k0i], statically indexed (full unroll)

#pragma unroll
    for (int h = 0; h < H_; ++h) {
        float sri = ((const float*)&sr4[i_my])[h];
        float mh  = lrelu(sri + ((id1[h] == i_my) ? mx2[h] : mx1[h]));
        // 32 exps (unnormalized P), diag zero, partial sum
        float p[4][8];
        float psum = 0.f;
#pragma unroll
        for (int k0i = 0; k0i < 4; ++k0i) {
            int jb = k0i * 32 + kg * 8;
            float4 sa = *(const float4*)&slh[h * 132 + jb];
            float4 sb = *(const float4*)&slh[h * 132 + jb + 4];
            float sj[8] = {sa.x, sa.y, sa.z, sa.w, sb.x, sb.y, sb.z, sb.w};
#pragma unroll
            for (int e = 0; e < 8; ++e) {
                int j = jb + e;
                float v = (j == i_my) ? 0.f : __expf(lrelu(sri + sj[e]) - mh);
                p[k0i][e] = v;
                psum += v;
            }
        }
        // full row sum across the 4 kg-lanes sharing this row
        psum += __shfl_xor(psum, 16);
        psum += __shfl_xor(psum, 32);
        float sh = 1.f / psum;
        // scale + pack (f16 RTN); same values feed MFMA and a_out
#pragma unroll
        for (int k0i = 0; k0i < 4; ++k0i) {
            union { unsigned short us[8]; uint4 v; } pk;
#pragma unroll
            for (int e = 0; e < 8; ++e) pk.us[e] = f2h(p[k0i][e] * sh);
            pa_all[h][k0i] = pk.v;
        }
        // PV MFMA
        __builtin_amdgcn_s_setprio(1);
#pragma unroll
        for (int k0i = 0; k0i < 4; ++k0i) {
            int koff = k0i * 32 + kg * 8;
#pragma unroll
            for (int n = 0; n < 8; ++n) {
                int f = n * 16 + ls;
                uint4 fb = *(const uint4*)&gt4[h * 16384 + f * 128 + (koff ^ swz)];
                aco[n] = mfma16h(pa_all[h][k0i], fb, aco[n]);
            }
        }
        __builtin_amdgcn_s_setprio(0);
    }

    // ---- a_out: float4-over-h, fully coalesced 16B stores ----
    {
        float* a_base = a_out + (size_t)sp * 65536 + (size_t)i_my * 512;  // [i][j][h]
#pragma unroll
        for (int k0i = 0; k0i < 4; ++k0i) {
            int jb = k0i * 32 + kg * 8;
#pragma unroll
            for (int e = 0; e < 8; ++e) {
                float4 av;
                av.x = h2f(((const unsigned short*)&pa_all[0][k0i])[e]);
                av.y = h2f(((const unsigned short*)&pa_all[1][k0i])[e]);
                av.z = h2f(((const unsigned short*)&pa_all[2][k0i])[e]);
                av.w = h2f(((const unsigned short*)&pa_all[3][k0i])[e]);
                *(float4*)&a_base[(jb + e) * 4] = av;
            }
        }
    }

    // ---- out epilogue ----
#pragma unroll
    for (int n = 0; n < 8; ++n) {
        int f = n * 16 + ls;
#pragma unroll
        for (int q = 0; q < 4; ++q)
            out[(size_t)(w * 16 + kg * 4 + q) * 65536 + (size_t)sp * NH_ + f] =
                aco[n][q] * 0.25f;
    }
}

// ---------------------------------------------------------------------------
extern "C" void kernel_launch(void* const* d_in, const int* in_sizes, int n_in,
                              void* d_out, int out_size, void* d_ws, size_t ws_size,
                              hipStream_t stream) {
    const float* hm = (const float*)d_in[0];
    const float* Wl = (const float*)d_in[1];
    const float* Wr = (const float*)d_in[2];
    const float* aw = (const float*)d_in[3];

    float* out   = (float*)d_out;
    float* a_out = out + OUT_ELEMS;

    char* ws = (char*)d_ws;
    float* sl  = (float*)ws;                                  // 1 MiB
    float* sr  = sl + SP_ * N_ * H_;                          // 1 MiB
    float* wls = sr + SP_ * N_ * H_;                          // 4 KiB
    float* wrs = wls + F_ * H_;                               // 4 KiB
    unsigned short* bth = (unsigned short*)(wrs + F_ * H_);   // 256 KiB
    unsigned short* btl = bth + GC_ * F_;                     // 256 KiB

    prep_kernel <<<8,           256, 0, stream>>>(Wl, Wr, aw, wls, wrs);
    prep_bt     <<<64,          256, 0, stream>>>(Wr, bth, btl);
    score_kernel<<<ROWS_ / 256, 256, 0, stream>>>(hm, wls, wrs, sl, sr);
    gat_fused   <<<SP_,         512, 0, stream>>>(sl, sr, hm, bth, btl, a_out, out);
}

// Round 17
// 144.743 us; speedup vs baseline: 1.6572x; 1.0157x over previous
//
#include <hip/hip_runtime.h>
#include <hip/hip_bf16.h>

#define DI __device__ __forceinline__

namespace {
constexpr int N_ = 128, S_ = 32, P_ = 16, F_ = 256, H_ = 4, NH_ = 128;
constexpr int SP_ = S_ * P_;          // 512
constexpr int ROWS_ = N_ * SP_;       // 65536
constexpr int GC_ = H_ * NH_;         // 512
constexpr float SLOPE_ = 0.2f;
constexpr int OUT_ELEMS = N_ * SP_ * NH_;    // 8,388,608
}

DI float lrelu(float x) { return fmaxf(x, SLOPE_ * x); }   // exact for slope<1

DI unsigned short f2h(float x) {
    _Float16 h = (_Float16)x;
    return __builtin_bit_cast(unsigned short, h);
}
DI float h2f(unsigned short b) {
    return (float)__builtin_bit_cast(_Float16, b);
}

typedef __fp16   fp16x2 __attribute__((ext_vector_type(2)));
typedef _Float16 f16x8 __attribute__((ext_vector_type(8)));
typedef float    f32x4 __attribute__((ext_vector_type(4)));

DI unsigned int pk2(float a, float b) {          // packed f16 convert (RTZ)
    fp16x2 r = __builtin_amdgcn_cvt_pkrtz(a, b);
    return __builtin_bit_cast(unsigned int, r);
}

DI f32x4 mfma16h(uint4 a, uint4 b, f32x4 c) {
    return __builtin_amdgcn_mfma_f32_16x16x32_f16(
        __builtin_bit_cast(f16x8, a), __builtin_bit_cast(f16x8, b), c, 0, 0, 0);
}

// ---------------------------------------------------------------------------
__global__ __launch_bounds__(256) void prep_kernel(
    const float* __restrict__ Wl, const float* __restrict__ Wr,
    const float* __restrict__ aw, float* __restrict__ wls, float* __restrict__ wrs) {
    int t = blockIdx.x * 256 + threadIdx.x;   // 0..2047
    int which = t >> 10;
    int f = (t & 1023) >> 2;
    int h = t & 3;
    const float* W = which ? Wr : Wl;
    const float* a = aw + which * NH_;
    const float* wrow = W + (size_t)f * GC_ + h * NH_;
    float s = 0.f;
    for (int k = 0; k < NH_; ++k) s += wrow[k] * a[k];
    (which ? wrs : wls)[f * H_ + h] = s;
}

// ---------------------------------------------------------------------------
__global__ __launch_bounds__(256) void prep_bt(
    const float* __restrict__ Wr, unsigned short* __restrict__ bth,
    unsigned short* __restrict__ btl) {
    int t = blockIdx.x * 256 + threadIdx.x;   // 0..16383
    int col = t >> 5, k0 = (t & 31) * 8;
    union { unsigned short us[8]; uint4 v; } ph, pl;
#pragma unroll
    for (int e = 0; e < 8; ++e) {
        float v = Wr[(size_t)(k0 + e) * GC_ + col] * 256.0f;
        unsigned short hi = f2h(v);
        ph.us[e] = hi;
        pl.us[e] = f2h(v - h2f(hi));
    }
    *(uint4*)&bth[col * F_ + k0] = ph.v;
    *(uint4*)&btl[col * F_ + k0] = pl.v;
}

// ---------------------------------------------------------------------------
__global__ __launch_bounds__(256) void score_kernel(
    const float* __restrict__ hm, const float* __restrict__ wls,
    const float* __restrict__ wrs, float* __restrict__ sl, float* __restrict__ sr) {
    int r = blockIdx.x * 256 + threadIdx.x;    // 0..65535
    const float4* hr  = (const float4*)(hm + (size_t)r * F_);
    const float4* wl4 = (const float4*)wls;
    const float4* wr4 = (const float4*)wrs;
    float4 al = {0.f,0.f,0.f,0.f}, ar = {0.f,0.f,0.f,0.f};
    for (int f0 = 0; f0 < F_; f0 += 4) {
        float4 hv = hr[f0 >> 2];
        float hx[4] = {hv.x, hv.y, hv.z, hv.w};
#pragma unroll
        for (int u = 0; u < 4; ++u) {
            float4 wl = wl4[f0 + u], wr = wr4[f0 + u];
            al.x += hx[u] * wl.x; al.y += hx[u] * wl.y;
            al.z += hx[u] * wl.z; al.w += hx[u] * wl.w;
            ar.x += hx[u] * wr.x; ar.y += hx[u] * wr.y;
            ar.z += hx[u] * wr.z; ar.w += hx[u] * wr.w;
        }
    }
    int n = r >> 9, sp = r & 511;
    ((float4*)sl)[sp * N_ + n] = al;
    ((float4*)sr)[sp * N_ + n] = ar;
}

// ---------------------------------------------------------------------------
// Fused per-sp kernel.  PV phase reordered so the a_out stores issue BEFORE
// the 4-head MFMA cluster (stores drain under MFMA, not at block-retire):
//   scores -> parallel max1/max2 -> pure-GEMM K-loop -> all-heads gt
//   epilogue (1 barrier) -> {exps+packs all heads} -> {a_out float4 stores}
//   -> {512 PV MFMAs, setprio} -> out epilogue.
__global__ __launch_bounds__(512, 2) void gat_fused(
    const float* __restrict__ sl_g, const float* __restrict__ sr_g,
    const float* __restrict__ hm,
    const unsigned short* __restrict__ bth, const unsigned short* __restrict__ btl,
    float* __restrict__ a_out, float* __restrict__ out) {
    constexpr int PA = 40;
    __shared__ __align__(16) unsigned char SMEM[136832];
    unsigned short* Ah0 = (unsigned short*)SMEM;               // [128*PA]
    unsigned short* Ah1 = Ah0 + 128 * PA;
    unsigned short* Al0 = Ah1 + 128 * PA;
    unsigned short* Al1 = Al0 + 128 * PA;                      // 40960 B total
    unsigned short* gt4 = (unsigned short*)SMEM;               // [4][128][128] after GEMM
    float4* sr4 = (float4*)(SMEM + 131072);                    // 2048 B
    float*  slh = (float*)(SMEM + 133120);                     // [4][132] = 2112 B
    float*  mx1 = (float*)(SMEM + 135232);
    float*  mx2 = (float*)(SMEM + 135248);
    int*    id1 = (int*)(SMEM + 135264);
    float*  pm1 = (float*)(SMEM + 135280);                     // [4][32]
    float*  pm2 = pm1 + 128;                                   // [4][32]
    int*    pid = (int*)(pm2 + 128);                           // [4][32]

    int sp = blockIdx.x;
    int t = threadIdx.x;
    int w = t >> 6, l = t & 63;
    int ls = l & 15, kg = l >> 4;

    // ---- load scores ----
    if (t < 128) {
        float4 v = ((const float4*)sl_g)[sp * N_ + t];
        slh[0 * 132 + t] = v.x; slh[1 * 132 + t] = v.y;
        slh[2 * 132 + t] = v.z; slh[3 * 132 + t] = v.w;
    } else if (t < 256) {
        sr4[t - 128] = ((const float4*)sr_g)[sp * N_ + (t - 128)];
    }
    __syncthreads();

    // ---- issue step-0 A loads early (drain under max-scan) ----
    int arow = t >> 2, akc = (t & 3) * 8;
    const float* abase = hm + ((size_t)arow * 512 + sp) * 256 + akc;
    float4 s0 = *(const float4*)(abase);
    float4 s1 = *(const float4*)(abase + 4);

    // ---- parallel max1/max2(+argmax) of sl per head ----
    if (t < 128) {
        int h = t >> 5, seg = t & 31;
        float m1 = -1e30f, m2 = -1e30f; int i1 = -1;
#pragma unroll
        for (int jj = 0; jj < 4; ++jj) {
            int j = seg * 4 + jj;
            float v = slh[h * 132 + j];
            if (v > m1) { m2 = m1; m1 = v; i1 = j; }
            else m2 = fmaxf(m2, v);
        }
        pm1[h * 32 + seg] = m1; pm2[h * 32 + seg] = m2; pid[h * 32 + seg] = i1;
    }
    __syncthreads();
    if (t < H_) {
        float m1 = -1e30f, m2 = -1e30f; int i1 = -1;
        for (int s = 0; s < 32; ++s) {
            float a1 = pm1[t * 32 + s], a2 = pm2[t * 32 + s]; int ai = pid[t * 32 + s];
            if (a1 > m1) { m2 = fmaxf(m1, a2); m1 = a1; i1 = ai; }
            else m2 = fmaxf(m2, a1);
        }
        mx1[t] = m1; mx2[t] = m2; id1[t] = i1;
    }

    // ---- convert + write A step-0 (pkrtz pairs) ----
    {
        float av[8] = {s0.x, s0.y, s0.z, s0.w, s1.x, s1.y, s1.z, s1.w};
        uint4 vh, vl;
        unsigned int* ph = (unsigned int*)&vh;
        unsigned int* pl = (unsigned int*)&vl;
#pragma unroll
        for (int e = 0; e < 8; e += 2) {
            unsigned int hp = pk2(av[e], av[e + 1]);
            float r0 = av[e]     - h2f((unsigned short)(hp & 0xffff));
            float r1 = av[e + 1] - h2f((unsigned short)(hp >> 16));
            ph[e >> 1] = hp;
            pl[e >> 1] = pk2(r0, r1);
        }
        *(uint4*)&Ah0[arow * PA + akc] = vh;
        *(uint4*)&Al0[arow * PA + akc] = vl;
    }
    __syncthreads();

    f32x4 acc[8][4];
#pragma unroll
    for (int m = 0; m < 8; ++m)
#pragma unroll
        for (int n = 0; n < 4; ++n) acc[m][n] = (f32x4){0.f, 0.f, 0.f, 0.f};

    // ---- pure-GEMM K-loop ----
    for (int step = 0; step < 8; ++step) {
        unsigned short* AhC = (step & 1) ? Ah1 : Ah0;
        unsigned short* AlC = (step & 1) ? Al1 : Al0;
        unsigned short* AhN = (step & 1) ? Ah0 : Ah1;
        unsigned short* AlN = (step & 1) ? Al0 : Al1;
        float4 n0, n1;
        if (step < 7) {
            n0 = *(const float4*)(abase + (step + 1) * 32);
            n1 = *(const float4*)(abase + (step + 1) * 32 + 4);
        }
        int kglob = step * 32 + kg * 8;
        uint4 fbh[4], fbl[4];
#pragma unroll
        for (int n = 0; n < 4; ++n) {
            int c = n * 128 + w * 16 + ls;
            fbh[n] = *(const uint4*)&bth[(size_t)c * F_ + kglob];
            fbl[n] = *(const uint4*)&btl[(size_t)c * F_ + kglob];
        }
#pragma unroll
        for (int m = 0; m < 8; ++m) {
            int row = m * 16 + ls;
            uint4 fah = *(const uint4*)&AhC[row * PA + kg * 8];
            uint4 fal = *(const uint4*)&AlC[row * PA + kg * 8];
#pragma unroll
            for (int n = 0; n < 4; ++n) {
                acc[m][n] = mfma16h(fah, fbh[n], acc[m][n]);
                acc[m][n] = mfma16h(fah, fbl[n], acc[m][n]);
                acc[m][n] = mfma16h(fal, fbh[n], acc[m][n]);
            }
        }
        if (step < 7) {
            float av[8] = {n0.x, n0.y, n0.z, n0.w, n1.x, n1.y, n1.z, n1.w};
            uint4 vh, vl;
            unsigned int* ph = (unsigned int*)&vh;
            unsigned int* pl = (unsigned int*)&vl;
#pragma unroll
            for (int e = 0; e < 8; e += 2) {
                unsigned int hp = pk2(av[e], av[e + 1]);
                float r0 = av[e]     - h2f((unsigned short)(hp & 0xffff));
                float r1 = av[e + 1] - h2f((unsigned short)(hp >> 16));
                ph[e >> 1] = hp;
                pl[e >> 1] = pk2(r0, r1);
            }
            *(uint4*)&AhN[arow * PA + akc] = vh;
            *(uint4*)&AlN[arow * PA + akc] = vl;
        }
        __syncthreads();
    }

    // ---- GEMM epilogue: all-heads gt (A buffers dead; union reuse) ----
    int fl  = w * 16 + ls;
    int swz = (ls & 7) << 3;
    constexpr float gs = 0.00390625f;
#pragma unroll
    for (int m = 0; m < 8; ++m) {
        int nx = (m * 16 + kg * 4) ^ swz;
#pragma unroll
        for (int h = 0; h < H_; ++h) {
            uint2 pk;
            pk.x = pk2(acc[m][h][0] * gs, acc[m][h][1] * gs);
            pk.y = pk2(acc[m][h][2] * gs, acc[m][h][3] * gs);
            *(uint2*)&gt4[h * 16384 + fl * 128 + nx] = pk;
        }
    }
    __syncthreads();

    // ---- PV phase part 1: exps + packs for ALL heads (no MFMA) ----
    int i_my = w * 16 + ls;
    uint4 pa_all[4][4];          // [head][k0i], statically indexed (full unroll)

#pragma unroll
    for (int h = 0; h < H_; ++h) {
        float sri = ((const float*)&sr4[i_my])[h];
        float mh  = lrelu(sri + ((id1[h] == i_my) ? mx2[h] : mx1[h]));
        float p[4][8];
        float psum = 0.f;
#pragma unroll
        for (int k0i = 0; k0i < 4; ++k0i) {
            int jb = k0i * 32 + kg * 8;
            float4 sa = *(const float4*)&slh[h * 132 + jb];
            float4 sb = *(const float4*)&slh[h * 132 + jb + 4];
            float sj[8] = {sa.x, sa.y, sa.z, sa.w, sb.x, sb.y, sb.z, sb.w};
#pragma unroll
            for (int e = 0; e < 8; ++e) {
                int j = jb + e;
                float v = (j == i_my) ? 0.f : __expf(lrelu(sri + sj[e]) - mh);
                p[k0i][e] = v;
                psum += v;
            }
        }
        psum += __shfl_xor(psum, 16);
        psum += __shfl_xor(psum, 32);
        float sh = 1.f / psum;
#pragma unroll
        for (int k0i = 0; k0i < 4; ++k0i) {
            union { unsigned short us[8]; uint4 v; } pk;
#pragma unroll
            for (int e = 0; e < 8; ++e) pk.us[e] = f2h(p[k0i][e] * sh);
            pa_all[h][k0i] = pk.v;
        }
    }

    // ---- PV phase part 2: a_out stores (issue now, drain under MFMA) ----
    {
        float* a_base = a_out + (size_t)sp * 65536 + (size_t)i_my * 512;  // [i][j][h]
#pragma unroll
        for (int k0i = 0; k0i < 4; ++k0i) {
            int jb = k0i * 32 + kg * 8;
#pragma unroll
            for (int e = 0; e < 8; ++e) {
                float4 av;
                av.x = h2f(((const unsigned short*)&pa_all[0][k0i])[e]);
                av.y = h2f(((const unsigned short*)&pa_all[1][k0i])[e]);
                av.z = h2f(((const unsigned short*)&pa_all[2][k0i])[e]);
                av.w = h2f(((const unsigned short*)&pa_all[3][k0i])[e]);
                *(float4*)&a_base[(jb + e) * 4] = av;
            }
        }
    }

    // ---- PV phase part 3: all 512 MFMAs (stores drain underneath) ----
    f32x4 aco[8];
#pragma unroll
    for (int n = 0; n < 8; ++n) aco[n] = (f32x4){0.f, 0.f, 0.f, 0.f};

    __builtin_amdgcn_s_setprio(1);
#pragma unroll
    for (int h = 0; h < H_; ++h) {
#pragma unroll
        for (int k0i = 0; k0i < 4; ++k0i) {
            int koff = k0i * 32 + kg * 8;
#pragma unroll
            for (int n = 0; n < 8; ++n) {
                int f = n * 16 + ls;
                uint4 fb = *(const uint4*)&gt4[h * 16384 + f * 128 + (koff ^ swz)];
                aco[n] = mfma16h(pa_all[h][k0i], fb, aco[n]);
            }
        }
    }
    __builtin_amdgcn_s_setprio(0);

    // ---- out epilogue ----
#pragma unroll
    for (int n = 0; n < 8; ++n) {
        int f = n * 16 + ls;
#pragma unroll
        for (int q = 0; q < 4; ++q)
            out[(size_t)(w * 16 + kg * 4 + q) * 65536 + (size_t)sp * NH_ + f] =
                aco[n][q] * 0.25f;
    }
}

// ---------------------------------------------------------------------------
extern "C" void kernel_launch(void* const* d_in, const int* in_sizes, int n_in,
                              void* d_out, int out_size, void* d_ws, size_t ws_size,
                              hipStream_t stream) {
    const float* hm = (const float*)d_in[0];
    const float* Wl = (const float*)d_in[1];
    const float* Wr = (const float*)d_in[2];
    const float* aw = (const float*)d_in[3];

    float* out   = (float*)d_out;
    float* a_out = out + OUT_ELEMS;

    char* ws = (char*)d_ws;
    float* sl  = (float*)ws;                                  // 1 MiB
    float* sr  = sl + SP_ * N_ * H_;                          // 1 MiB
    float* wls = sr + SP_ * N_ * H_;                          // 4 KiB
    float* wrs = wls + F_ * H_;                               // 4 KiB
    unsigned short* bth = (unsigned short*)(wrs + F_ * H_);   // 256 KiB
    unsigned short* btl = bth + GC_ * F_;                     // 256 KiB

    prep_kernel <<<8,           256, 0, stream>>>(Wl, Wr, aw, wls, wrs);
    prep_bt     <<<64,          256, 0, stream>>>(Wr, bth, btl);
    score_kernel<<<ROWS_ / 256, 256, 0, stream>>>(hm, wls, wrs, sl, sr);
    gat_fused   <<<SP_,         512, 0, stream>>>(sl, sr, hm, bth, btl, a_out, out);
}